// Round 5
// baseline (4795.020 us; speedup 1.0000x reference)
//
#include <hip/hip_runtime.h>
#include <hip/hip_bf16.h>

// ============================================================================
// DIAGNOSTIC ROUND 2: time-ruler (+800us pad) on conv1/conv2/pool/meancov/
// reduce. third_kernel unpadded (known: real ~259us from R4 ruler).
// Decode: real_us = dur_us - 800. All real work identical to round 3.
// ============================================================================

// Problem constants
#define BB   64
#define CIN  3
#define HH   224
#define WW   224
#define C1   32
#define H1   112
#define W1   112
#define C2   64
#define H2   56
#define W2   56
#define FEATN 64
#define OUTN 1024
#define K3TOT (FEATN*FEATN*FEATN)   // 262144

typedef __bf16 bf16x8 __attribute__((ext_vector_type(8)));
typedef float  f32x4  __attribute__((ext_vector_type(4)));
typedef unsigned int u32;

__device__ __forceinline__ void gload_lds16(const void* g, void* l) {
  __builtin_amdgcn_global_load_lds((const __attribute__((address_space(1))) u32*)g,
                                   (__attribute__((address_space(3))) u32*)l, 16, 0, 0);
}

// ---- time ruler: block 0 waits for all blocks, then spins PAD_TICKS ---------
#define PAD_TICKS   80000ULL      // ~800 us @ 100 MHz s_memrealtime (confirmed R4)
#define PAD_TIMEOUT 1200000ULL    // 12 ms safety cap on the done-wait
__device__ __forceinline__ void time_ruler(unsigned int* cnt, unsigned int grid) {
  __syncthreads();
  if (threadIdx.x == 0) {
    atomicAdd(cnt, 1u);                              // device-scope by default
    if (blockIdx.x == 0) {
      unsigned long long t0 = __builtin_amdgcn_s_memrealtime();
      while (__hip_atomic_load(cnt, __ATOMIC_RELAXED, __HIP_MEMORY_SCOPE_AGENT)
               < grid &&
             __builtin_amdgcn_s_memrealtime() - t0 < PAD_TIMEOUT) {}
      unsigned long long t1 = __builtin_amdgcn_s_memrealtime();
      while (__builtin_amdgcn_s_memrealtime() - t1 < PAD_TICKS) {}
    }
  }
}

// -------- zero the pad counters (runs first, every launch) --------------------
__global__ void zero_cnt_kernel(unsigned int* c) {
    if (threadIdx.x < 8) c[threadIdx.x] = 0u;
}

// ---------------- conv1: (64,3,224,224) -> relu -> (64,32,112,112), s=2 p=1 ----
#define CONV1_GRID 3136
__global__ __launch_bounds__(256) void conv1_kernel(const float* __restrict__ x,
        const float* __restrict__ w1, const float* __restrict__ b1,
        float* __restrict__ h1, unsigned int* __restrict__ cnt) {
    int pos = blockIdx.x * 256 + threadIdx.x;        // 64*112*112 = 802816
    int b   = pos / (H1 * W1);
    int rem = pos - b * (H1 * W1);
    int oy  = rem / W1;
    int ox  = rem - oy * W1;
    int iy0 = oy * 2 - 1, ix0 = ox * 2 - 1;

    float win[27];
    #pragma unroll
    for (int c = 0; c < CIN; ++c)
      #pragma unroll
      for (int dy = 0; dy < 3; ++dy)
        #pragma unroll
        for (int dx = 0; dx < 3; ++dx) {
          int iy = iy0 + dy, ix = ix0 + dx;
          bool ok = (iy >= 0) & (iy < HH) & (ix >= 0) & (ix < WW);
          win[c*9 + dy*3 + dx] = ok ? x[((b*CIN + c)*HH + iy)*WW + ix] : 0.f;
        }

    #pragma unroll 4
    for (int oc = 0; oc < C1; ++oc) {
      float acc = b1[oc];
      #pragma unroll
      for (int q = 0; q < 27; ++q)
        acc = fmaf(w1[oc*27 + q], win[q], acc);
      h1[((b*C1 + oc)*H1 + oy)*W1 + ox] = fmaxf(acc, 0.f);
    }
    time_ruler(cnt + 0, CONV1_GRID);
}

// ---------------- conv2: (64,32,112,112) -> relu -> (64,64,56,56), s=2 p=1 -----
#define CONV2_GRID 784
__global__ __launch_bounds__(256) void conv2_kernel(const float* __restrict__ h1,
        const float* __restrict__ w2, const float* __restrict__ b2,
        float* __restrict__ h2, unsigned int* __restrict__ cnt) {
    int pos = blockIdx.x * 256 + threadIdx.x;        // 64*56*56 = 200704
    int b   = pos / (H2 * W2);
    int rem = pos - b * (H2 * W2);
    int oy  = rem / W2;
    int ox  = rem - oy * W2;
    int iy0 = oy * 2 - 1, ix0 = ox * 2 - 1;

    float acc[C2];
    #pragma unroll
    for (int oc = 0; oc < C2; ++oc) acc[oc] = b2[oc];

    for (int c = 0; c < C1; ++c) {                   // 32 input channels
      float win[9];
      #pragma unroll
      for (int dy = 0; dy < 3; ++dy)
        #pragma unroll
        for (int dx = 0; dx < 3; ++dx) {
          int iy = iy0 + dy, ix = ix0 + dx;
          bool ok = (iy >= 0) & (iy < H1) & (ix >= 0) & (ix < W1);
          win[dy*3 + dx] = ok ? h1[((b*C1 + c)*H1 + iy)*W1 + ix] : 0.f;
        }
      #pragma unroll
      for (int oc = 0; oc < C2; ++oc) {
        #pragma unroll
        for (int q = 0; q < 9; ++q)
          acc[oc] = fmaf(w2[(oc*C1 + c)*9 + q], win[q], acc[oc]);
      }
    }
    #pragma unroll
    for (int oc = 0; oc < C2; ++oc)
      h2[((b*C2 + oc)*H2 + oy)*W2 + ox] = fmaxf(acc[oc], 0.f);
    time_ruler(cnt + 1, CONV2_GRID);
}

// ---------------- global average pool: (64,64,56,56) -> feat (64,64) ----------
#define POOL_GRID 4096
__global__ __launch_bounds__(256) void pool_kernel(const float* __restrict__ h2,
        float* __restrict__ feat, unsigned int* __restrict__ cnt) {
    int bc = blockIdx.x;                             // 0..4095 = b*64 + c
    const float* p = h2 + (size_t)bc * (H2 * W2);
    float s = 0.f;
    for (int i = threadIdx.x; i < H2 * W2; i += 256) s += p[i];
    #pragma unroll
    for (int off = 32; off; off >>= 1) s += __shfl_down(s, off);
    __shared__ float red[4];
    if ((threadIdx.x & 63) == 0) red[threadIdx.x >> 6] = s;
    __syncthreads();
    if (threadIdx.x == 0)
      feat[bc] = (red[0] + red[1] + red[2] + red[3]) * (1.f / (H2 * W2));
    time_ruler(cnt + 2, POOL_GRID);
}

// ---------------- center: fc = feat - rowmean(feat) ---------------------------
__global__ __launch_bounds__(64) void center_kernel(const float* __restrict__ feat,
        float* __restrict__ fc) {
    __shared__ float fl[FEATN * FEATN];
    int t = threadIdx.x;                             // 64 threads; t = b
    for (int i = t; i < FEATN * FEATN; i += 64) fl[i] = feat[i];
    __syncthreads();
    float m = 0.f;
    for (int c = 0; c < FEATN; ++c) m += fl[t*FEATN + c];
    m *= (1.f / FEATN);
    for (int c = 0; c < FEATN; ++c) fc[t*FEATN + c] = fl[t*FEATN + c] - m;
}

// -------- mean_feat + cov_feat + all biases -> WRITES d_out -------------------
#define MEANCOV_GRID 256
__global__ __launch_bounds__(256) void meancov_kernel(const float* __restrict__ feat,
        const float* __restrict__ fc,
        const float* __restrict__ wm, const float* __restrict__ bm,
        const float* __restrict__ wc, const float* __restrict__ bcv,
        const float* __restrict__ b3, float* __restrict__ out,
        unsigned int* __restrict__ cnt) {
    __shared__ float featT[FEATN * FEATN];           // [c][b]
    __shared__ float fcT[FEATN * FEATN];             // [c][b]
    int t = threadIdx.x;
    for (int i = t; i < FEATN * FEATN; i += 256) {
      int b = i >> 6, c = i & 63;
      featT[c*64 + b] = feat[i];
      fcT[c*64 + b]   = fc[i];
    }
    __syncthreads();

    int b = t & 63;
    int o = blockIdx.x * 4 + (t >> 6);               // 256 blocks * 4 = 1024

    float fr[64];                                    // fc[b][*] in registers
    #pragma unroll
    for (int c4 = 0; c4 < 16; ++c4) {
      float4 v = *(const float4*)(fc + b*64 + c4*4);
      fr[c4*4+0]=v.x; fr[c4*4+1]=v.y; fr[c4*4+2]=v.z; fr[c4*4+3]=v.w;
    }

    float acc = bm[o] + bcv[o] + b3[o];
    #pragma unroll 8
    for (int c = 0; c < FEATN; ++c)
      acc = fmaf(featT[c*64 + b], wm[o*FEATN + c], acc);

    const float* wcrow = wc + (size_t)o * (FEATN * FEATN);
    #pragma unroll 1
    for (int c1 = 0; c1 < 64; ++c1) {
      float a2 = 0.f;
      #pragma unroll
      for (int c2 = 0; c2 < 64; ++c2)                // fr[c2]: static index
        a2 = fmaf(fr[c2], wcrow[c1*64 + c2], a2);
      acc = fmaf(fcT[c1*64 + b], a2, acc);           // LDS: 64 reads total
    }
    out[b * OUTN + o] = acc;
    time_ruler(cnt + 3, MEANCOV_GRID);
}

// -------- third-order term (unpadded, identical to round 3) -------------------
#define T3_NBLK 32
#define KSLICES 128
#define CHUNK_IJ 2
#define NCHUNK 16           // 32 ij-pairs / CHUNK_IJ
#define T3_GRID (T3_NBLK * KSLICES)

struct T3Shared {
    float stage[2][32][CHUNK_IJ*64];   // [buf][block-col][k]  (32 KB)
    float fcJ[32][65];                 // fc[b][jbase+jl] as [jl][b], padded
    float fcI[64];                     // fc[b][i0]
};

__device__ __forceinline__ void t3_issue(const char* w3b, float (*buf)[CHUNK_IJ*64],
        int wave, int ocolbase, size_t kb, int lane) {
    int hi = lane >> 5;                 // which of the 2 cols this lane feeds
    int lo = (lane & 31) * 16;          // byte within the column's 512-B span
    #pragma unroll
    for (int i = 0; i < 8; ++i) {
      int colb = wave*16 + 2*i;         // block-local col of this inst (even)
      int col  = colb + hi;
      // inverse-swizzle the SOURCE so a swizzled READ sees w3[col][kb+koff]
      int srcoff = lo ^ ((col & 7) << 4);
      const char* src = w3b + (((size_t)(ocolbase + col)) << 20) + kb + srcoff;
      gload_lds16(src, &buf[colb][0]);
    }
}

__device__ __forceinline__ void t3_compute(const float (*buf)[CHUNK_IJ*64],
        const float (*fcJ)[65], const float* fcI,
        int c, int wave, int lane, const float4 aA[4][2], const float4 aB[4][2],
        f32x4 acc[4]) {
    int l15 = lane & 15, l4 = lane >> 4;
    int col = wave*16 + l15;
    int swz = (col & 7) << 4;
    int x0 = (l4*32) ^ swz;
    int x1 = (l4*32 + 16) ^ swz;
    const char* p = (const char*)&buf[col][0];
    #pragma unroll
    for (int e = 0; e < CHUNK_IJ; ++e) {
      int jl = c*CHUNK_IJ + e;
      float smul[4];
      #pragma unroll
      for (int m = 0; m < 4; ++m) {
        int bb = m*16 + l15;
        smul[m] = fcI[bb] * fcJ[jl][bb];
      }
      #pragma unroll
      for (int s = 0; s < 2; ++s) {
        int K = e*256 + s*128;                       // static after unroll
        float4 b0 = *(const float4*)(p + K + x0);
        float4 b1 = *(const float4*)(p + K + x1);
        bf16x8 bfrag;
        bfrag[0] = (__bf16)b0.x; bfrag[1] = (__bf16)b0.y;
        bfrag[2] = (__bf16)b0.z; bfrag[3] = (__bf16)b0.w;
        bfrag[4] = (__bf16)b1.x; bfrag[5] = (__bf16)b1.y;
        bfrag[6] = (__bf16)b1.z; bfrag[7] = (__bf16)b1.w;
        #pragma unroll
        for (int m = 0; m < 4; ++m) {
          float sc = smul[m];
          bf16x8 afrag;
          afrag[0] = (__bf16)(aA[m][s].x * sc); afrag[1] = (__bf16)(aA[m][s].y * sc);
          afrag[2] = (__bf16)(aA[m][s].z * sc); afrag[3] = (__bf16)(aA[m][s].w * sc);
          afrag[4] = (__bf16)(aB[m][s].x * sc); afrag[5] = (__bf16)(aB[m][s].y * sc);
          afrag[6] = (__bf16)(aB[m][s].z * sc); afrag[7] = (__bf16)(aB[m][s].w * sc);
          acc[m] = __builtin_amdgcn_mfma_f32_16x16x32_bf16(afrag, bfrag, acc[m], 0, 0, 0);
        }
      }
    }
}

#define T3_WAIT(N) do { asm volatile("s_waitcnt vmcnt(" #N ")" ::: "memory"); \
                        __builtin_amdgcn_sched_barrier(0); } while (0)

__global__ __launch_bounds__(128) void third_kernel(const float* __restrict__ fc,
        const float* __restrict__ w3, float* __restrict__ part) {
    __shared__ T3Shared sh;
    int t = threadIdx.x;
    int nblk   = blockIdx.x & (T3_NBLK - 1);
    int kslice = blockIdx.x >> 5;
    int i0     = kslice >> 1;                        // i is constant per kslice
    int jbase  = (kslice & 1) * 32;

    // stage fcJ (transposed, padded) and fcI
    for (int idx = t; idx < 32*64; idx += 128) {
      int b = idx >> 5, jl = idx & 31;               // contiguous 32-float reads
      sh.fcJ[jl][b] = fc[b*64 + jbase + jl];
    }
    if (t < 64) sh.fcI[t] = fc[t*64 + i0];
    __syncthreads();                                 // drains vmcnt too

    int wave = t >> 6;
    int lane = t & 63;
    int l15  = lane & 15;
    int l4   = lane >> 4;
    int ocolbase = nblk * 32;

    // Hoisted raw A fragments: fc[m*16+l15][(s*4+l4)*8 .. +8)
    float4 aA[4][2], aB[4][2];
    #pragma unroll
    for (int m = 0; m < 4; ++m)
      #pragma unroll
      for (int s = 0; s < 2; ++s) {
        const float* pa = fc + (m*16 + l15)*64 + (s*4 + l4)*8;
        aA[m][s] = *(const float4*)pa;
        aB[m][s] = *(const float4*)(pa + 4);
      }

    f32x4 acc[4];
    #pragma unroll
    for (int m = 0; m < 4; ++m) acc[m] = (f32x4){0.f, 0.f, 0.f, 0.f};

    const char* w3b = (const char*)w3;
    size_t kb0 = (size_t)kslice * 8192;              // byte offset within column
    #define KB(c) (kb0 + (size_t)(c) * (CHUNK_IJ*64*4))

    t3_issue(w3b, sh.stage[0], wave, ocolbase, KB(0), lane);
    #pragma unroll 1
    for (int c = 0; c < NCHUNK - 2; c += 2) {
      t3_issue(w3b, sh.stage[1], wave, ocolbase, KB(c+1), lane);
      T3_WAIT(8);
      t3_compute(sh.stage[0], sh.fcJ, sh.fcI, c, wave, lane, aA, aB, acc);
      t3_issue(w3b, sh.stage[0], wave, ocolbase, KB(c+2), lane);
      T3_WAIT(8);
      t3_compute(sh.stage[1], sh.fcJ, sh.fcI, c+1, wave, lane, aA, aB, acc);
    }
    t3_issue(w3b, sh.stage[1], wave, ocolbase, KB(NCHUNK-1), lane);
    T3_WAIT(8);
    t3_compute(sh.stage[0], sh.fcJ, sh.fcI, NCHUNK-2, wave, lane, aA, aB, acc);
    T3_WAIT(0);
    t3_compute(sh.stage[1], sh.fcJ, sh.fcI, NCHUNK-1, wave, lane, aA, aB, acc);

    // D layout (verified m89): col = lane&15, row = (lane>>4)*4 + reg
    float* pt = part + (size_t)kslice * 64 * OUTN;
    int ocol = ocolbase + wave*16 + l15;
    #pragma unroll
    for (int m = 0; m < 4; ++m)
      #pragma unroll
      for (int r = 0; r < 4; ++r) {
        int row = m*16 + l4*4 + r;                   // batch
        pt[row * OUTN + ocol] = acc[m][r];
      }
}

// -------- sum the 128 K-slice partials into d_out ------------------------------
#define REDUCE_GRID 256
__global__ __launch_bounds__(256) void reduce_kernel(const float* __restrict__ part,
        float* __restrict__ out, unsigned int* __restrict__ cnt) {
    int idx = blockIdx.x * 256 + threadIdx.x;        // 65536 = 64*1024
    float s = 0.f;
    #pragma unroll 8
    for (int ks = 0; ks < KSLICES; ++ks)
      s += part[(size_t)ks * (64 * OUTN) + idx];
    out[idx] += s;
    time_ruler(cnt + 4, REDUCE_GRID);
}

extern "C" void kernel_launch(void* const* d_in, const int* in_sizes, int n_in,
                              void* d_out, int out_size, void* d_ws, size_t ws_size,
                              hipStream_t stream) {
    const float* x   = (const float*)d_in[0];
    const float* w1  = (const float*)d_in[1];
    const float* b1  = (const float*)d_in[2];
    const float* w2  = (const float*)d_in[3];
    const float* b2  = (const float*)d_in[4];
    const float* wm  = (const float*)d_in[5];
    const float* bm  = (const float*)d_in[6];
    const float* wc  = (const float*)d_in[7];
    const float* bcv = (const float*)d_in[8];
    const float* w3  = (const float*)d_in[9];
    const float* b3  = (const float*)d_in[10];
    float* out = (float*)d_out;

    // workspace layout (floats): h1 | h2 | feat | fc | part | cnt
    float* ws   = (float*)d_ws;
    float* h1   = ws;                                // 64*32*112*112 = 25690112
    float* h2   = ws + 25690112;                     // 64*64*56*56   = 12845056
    float* feat = ws + 38535168;                     // 4096
    float* fcv  = ws + 38539264;                     // 4096
    float* part = ws + 38543360;                     // 128*64*1024   = 8388608
    unsigned int* cnt = (unsigned int*)(ws + 46931968);

    zero_cnt_kernel<<<1, 64, 0, stream>>>(cnt);
    conv1_kernel <<<CONV1_GRID, 256, 0, stream>>>(x, w1, b1, h1, cnt);
    conv2_kernel <<<CONV2_GRID, 256, 0, stream>>>(h1, w2, b2, h2, cnt);
    pool_kernel  <<<POOL_GRID, 256, 0, stream>>>(h2, feat, cnt);
    center_kernel<<<1, 64, 0, stream>>>(feat, fcv);
    meancov_kernel<<<MEANCOV_GRID, 256, 0, stream>>>(feat, fcv, wm, bm, wc, bcv, b3, out, cnt);
    third_kernel <<<T3_GRID, 128, 0, stream>>>(fcv, w3, part);
    reduce_kernel<<<REDUCE_GRID, 256, 0, stream>>>(part, out, cnt);
}

// Round 6
// 579.596 us; speedup vs baseline: 8.2730x; 8.2730x over previous
//
#include <hip/hip_runtime.h>
#include <hip/hip_bf16.h>

// Problem constants
#define BB   64
#define CIN  3
#define HH   224
#define WW   224
#define C1   32
#define H1   112
#define W1   112
#define C2   64
#define H2   56
#define W2   56
#define FEATN 64
#define OUTN 1024
#define K3TOT (FEATN*FEATN*FEATN)   // 262144

typedef __bf16 bf16x8 __attribute__((ext_vector_type(8)));
typedef float  f32x4  __attribute__((ext_vector_type(4)));
typedef unsigned int u32;

__device__ __forceinline__ void gload_lds16(const void* g, void* l) {
  __builtin_amdgcn_global_load_lds((const __attribute__((address_space(1))) u32*)g,
                                   (__attribute__((address_space(3))) u32*)l, 16, 0, 0);
}

// ---------------- conv1: (64,3,224,224) -> relu -> (64,32,112,112), s=2 p=1 ----
__global__ __launch_bounds__(256) void conv1_kernel(const float* __restrict__ x,
        const float* __restrict__ w1, const float* __restrict__ b1,
        float* __restrict__ h1) {
    int pos = blockIdx.x * 256 + threadIdx.x;        // 64*112*112 = 802816
    int b   = pos / (H1 * W1);
    int rem = pos - b * (H1 * W1);
    int oy  = rem / W1;
    int ox  = rem - oy * W1;
    int iy0 = oy * 2 - 1, ix0 = ox * 2 - 1;

    float win[27];
    #pragma unroll
    for (int c = 0; c < CIN; ++c)
      #pragma unroll
      for (int dy = 0; dy < 3; ++dy)
        #pragma unroll
        for (int dx = 0; dx < 3; ++dx) {
          int iy = iy0 + dy, ix = ix0 + dx;
          bool ok = (iy >= 0) & (iy < HH) & (ix >= 0) & (ix < WW);
          win[c*9 + dy*3 + dx] = ok ? x[((b*CIN + c)*HH + iy)*WW + ix] : 0.f;
        }

    #pragma unroll 4
    for (int oc = 0; oc < C1; ++oc) {
      float acc = b1[oc];
      #pragma unroll
      for (int q = 0; q < 27; ++q)
        acc = fmaf(w1[oc*27 + q], win[q], acc);
      h1[((b*C1 + oc)*H1 + oy)*W1 + ox] = fmaxf(acc, 0.f);
    }
}

// ---------------- conv2 (REWRITE): LDS-tiled, lane=oc, acc[2][8] in VGPRs -----
// Block: 256 thr = 1 batch x 8x8 output tile x all 64 oc.
// LDS: input tile [32][17][20] (rows padded to 20 floats -> 16B-aligned b128).
// Wave w computes output rows oy0+2w, oy0+2w+1, all 8 x; lane = oc.
// Epilogue: LDS bounce (65-pad, conflict-free) -> float4-coalesced h2 stores.
#define C2_LDSF 10880   // 32*17*20 floats = 43520 B
__global__ __launch_bounds__(256) void conv2_kernel(const float* __restrict__ h1,
        const float* __restrict__ w2, const float* __restrict__ b2,
        float* __restrict__ h2) {
    __shared__ float lds[C2_LDSF];
    int t   = threadIdx.x;
    int bid = blockIdx.x;                            // 64*7*7 = 3136
    int b   = bid / 49;
    int rem = bid - b * 49;
    int ty  = rem / 7;
    int tx  = rem - ty * 7;
    int oy0 = ty * 8, ox0 = tx * 8;

    // ---- stage input tile: local (c, iy, ix) <- h1[b, c, 2*oy0-1+iy, 2*ox0-1+ix]
    for (int idx = t; idx < 32 * 289; idx += 256) {
      int c  = idx / 289;
      int r2 = idx - c * 289;
      int iy = r2 / 17;
      int ix = r2 - iy * 17;
      int giy = 2 * oy0 - 1 + iy;
      int gix = 2 * ox0 - 1 + ix;
      bool ok = (giy >= 0) & (giy < H1) & (gix >= 0) & (gix < W1);
      lds[c * 340 + iy * 20 + ix] =
          ok ? h1[((b * C1 + c) * H1 + giy) * W1 + gix] : 0.f;
    }
    __syncthreads();

    int w    = t >> 6;                               // wave id: output row pair
    int lane = t & 63;
    int oc   = lane;
    const float* w2p = w2 + oc * 288;                // w2[oc][c][3][3]

    float acc[2][8];
    #pragma unroll
    for (int r = 0; r < 2; ++r)
      #pragma unroll
      for (int x = 0; x < 8; ++x) acc[r][x] = 0.f;

    #pragma unroll 1
    for (int c = 0; c < 32; ++c) {
      float wr[9];
      #pragma unroll
      for (int q = 0; q < 9; ++q) wr[q] = w2p[c * 9 + q];
      const float* lr = lds + c * 340 + (w * 4) * 20;  // wave's input row base
      #pragma unroll
      for (int r = 0; r < 2; ++r) {
        float rwf[3][17];
        #pragma unroll
        for (int rr = 0; rr < 3; ++rr) {
          const float* rp = lr + (2 * r + rr) * 20;
          #pragma unroll
          for (int kk = 0; kk < 4; ++kk) {
            float4 v = *(const float4*)(rp + kk * 4);
            rwf[rr][kk*4+0] = v.x; rwf[rr][kk*4+1] = v.y;
            rwf[rr][kk*4+2] = v.z; rwf[rr][kk*4+3] = v.w;
          }
          rwf[rr][16] = rp[16];
        }
        #pragma unroll
        for (int x = 0; x < 8; ++x)
          #pragma unroll
          for (int dy = 0; dy < 3; ++dy)
            #pragma unroll
            for (int dx = 0; dx < 3; ++dx)
              acc[r][x] = fmaf(wr[dy*3+dx], rwf[dy][2*x+dx], acc[r][x]);
      }
    }

    // ---- epilogue: bias+relu, LDS bounce (pad 65 -> conflict-free scatter),
    //      then float4-coalesced stores
    float bias = b2[oc];
    __syncthreads();                                 // staging reads done
    #pragma unroll
    for (int r = 0; r < 2; ++r)
      #pragma unroll
      for (int x = 0; x < 8; ++x)
        lds[oc * 65 + (2 * w + r) * 8 + x] = fmaxf(acc[r][x] + bias, 0.f);
    __syncthreads();

    #pragma unroll
    for (int k = 0; k < 2; ++k) {
      int R  = t * 2 + k;                            // 0..511 = oc*8 + row
      int o2 = R >> 3;
      int r2 = R & 7;
      const float* src = lds + o2 * 65 + r2 * 8;
      float4 v0 = *(const float4*)(src);
      float4 v1 = *(const float4*)(src + 4);
      float* dst = h2 + ((size_t)(b * C2 + o2) * H2 + oy0 + r2) * W2 + ox0;
      *(float4*)(dst)     = v0;
      *(float4*)(dst + 4) = v1;
    }
}

// ---------------- global average pool: (64,64,56,56) -> feat (64,64) ----------
__global__ __launch_bounds__(256) void pool_kernel(const float* __restrict__ h2,
        float* __restrict__ feat) {
    int bc = blockIdx.x;                             // 0..4095 = b*64 + c
    const float* p = h2 + (size_t)bc * (H2 * W2);
    float s = 0.f;
    for (int i = threadIdx.x; i < H2 * W2; i += 256) s += p[i];
    #pragma unroll
    for (int off = 32; off; off >>= 1) s += __shfl_down(s, off);
    __shared__ float red[4];
    if ((threadIdx.x & 63) == 0) red[threadIdx.x >> 6] = s;
    __syncthreads();
    if (threadIdx.x == 0)
      feat[bc] = (red[0] + red[1] + red[2] + red[3]) * (1.f / (H2 * W2));
}

// ---------------- center: fc = feat - rowmean(feat) ---------------------------
__global__ __launch_bounds__(64) void center_kernel(const float* __restrict__ feat,
        float* __restrict__ fc) {
    __shared__ float fl[FEATN * FEATN];
    int t = threadIdx.x;                             // 64 threads; t = b
    for (int i = t; i < FEATN * FEATN; i += 64) fl[i] = feat[i];
    __syncthreads();
    float m = 0.f;
    for (int c = 0; c < FEATN; ++c) m += fl[t*FEATN + c];
    m *= (1.f / FEATN);
    for (int c = 0; c < FEATN; ++c) fc[t*FEATN + c] = fl[t*FEATN + c] - m;
}

// -------- mean_feat + cov_feat + all biases -> WRITES d_out -------------------
__global__ __launch_bounds__(256) void meancov_kernel(const float* __restrict__ feat,
        const float* __restrict__ fc,
        const float* __restrict__ wm, const float* __restrict__ bm,
        const float* __restrict__ wc, const float* __restrict__ bcv,
        const float* __restrict__ b3, float* __restrict__ out) {
    __shared__ float featT[FEATN * FEATN];           // [c][b]
    __shared__ float fcT[FEATN * FEATN];             // [c][b]
    int t = threadIdx.x;
    for (int i = t; i < FEATN * FEATN; i += 256) {
      int b = i >> 6, c = i & 63;
      featT[c*64 + b] = feat[i];
      fcT[c*64 + b]   = fc[i];
    }
    __syncthreads();

    int b = t & 63;
    int o = blockIdx.x * 4 + (t >> 6);               // 256 blocks * 4 = 1024

    float fr[64];                                    // fc[b][*] in registers
    #pragma unroll
    for (int c4 = 0; c4 < 16; ++c4) {
      float4 v = *(const float4*)(fc + b*64 + c4*4);
      fr[c4*4+0]=v.x; fr[c4*4+1]=v.y; fr[c4*4+2]=v.z; fr[c4*4+3]=v.w;
    }

    float acc = bm[o] + bcv[o] + b3[o];
    #pragma unroll 8
    for (int c = 0; c < FEATN; ++c)
      acc = fmaf(featT[c*64 + b], wm[o*FEATN + c], acc);

    const float* wcrow = wc + (size_t)o * (FEATN * FEATN);
    #pragma unroll 1
    for (int c1 = 0; c1 < 64; ++c1) {
      float a2 = 0.f;
      #pragma unroll
      for (int c2 = 0; c2 < 64; ++c2)                // fr[c2]: static index
        a2 = fmaf(fr[c2], wcrow[c1*64 + c2], a2);
      acc = fmaf(fcT[c1*64 + b], a2, acc);           // LDS: 64 reads total
    }
    out[b * OUTN + o] = acc;
}

// -------- third-order term (identical to round 3; known-good, ~259us) ---------
#define T3_NBLK 32
#define KSLICES 128
#define CHUNK_IJ 2
#define NCHUNK 16           // 32 ij-pairs / CHUNK_IJ
#define T3_GRID (T3_NBLK * KSLICES)

struct T3Shared {
    float stage[2][32][CHUNK_IJ*64];   // [buf][block-col][k]  (32 KB)
    float fcJ[32][65];                 // fc[b][jbase+jl] as [jl][b], padded
    float fcI[64];                     // fc[b][i0]
};

__device__ __forceinline__ void t3_issue(const char* w3b, float (*buf)[CHUNK_IJ*64],
        int wave, int ocolbase, size_t kb, int lane) {
    int hi = lane >> 5;                 // which of the 2 cols this lane feeds
    int lo = (lane & 31) * 16;          // byte within the column's 512-B span
    #pragma unroll
    for (int i = 0; i < 8; ++i) {
      int colb = wave*16 + 2*i;         // block-local col of this inst (even)
      int col  = colb + hi;
      // inverse-swizzle the SOURCE so a swizzled READ sees w3[col][kb+koff]
      int srcoff = lo ^ ((col & 7) << 4);
      const char* src = w3b + (((size_t)(ocolbase + col)) << 20) + kb + srcoff;
      gload_lds16(src, &buf[colb][0]);
    }
}

__device__ __forceinline__ void t3_compute(const float (*buf)[CHUNK_IJ*64],
        const float (*fcJ)[65], const float* fcI,
        int c, int wave, int lane, const float4 aA[4][2], const float4 aB[4][2],
        f32x4 acc[4]) {
    int l15 = lane & 15, l4 = lane >> 4;
    int col = wave*16 + l15;
    int swz = (col & 7) << 4;
    int x0 = (l4*32) ^ swz;
    int x1 = (l4*32 + 16) ^ swz;
    const char* p = (const char*)&buf[col][0];
    #pragma unroll
    for (int e = 0; e < CHUNK_IJ; ++e) {
      int jl = c*CHUNK_IJ + e;
      float smul[4];
      #pragma unroll
      for (int m = 0; m < 4; ++m) {
        int bb = m*16 + l15;
        smul[m] = fcI[bb] * fcJ[jl][bb];
      }
      #pragma unroll
      for (int s = 0; s < 2; ++s) {
        int K = e*256 + s*128;                       // static after unroll
        float4 b0 = *(const float4*)(p + K + x0);
        float4 b1 = *(const float4*)(p + K + x1);
        bf16x8 bfrag;
        bfrag[0] = (__bf16)b0.x; bfrag[1] = (__bf16)b0.y;
        bfrag[2] = (__bf16)b0.z; bfrag[3] = (__bf16)b0.w;
        bfrag[4] = (__bf16)b1.x; bfrag[5] = (__bf16)b1.y;
        bfrag[6] = (__bf16)b1.z; bfrag[7] = (__bf16)b1.w;
        #pragma unroll
        for (int m = 0; m < 4; ++m) {
          float sc = smul[m];
          bf16x8 afrag;
          afrag[0] = (__bf16)(aA[m][s].x * sc); afrag[1] = (__bf16)(aA[m][s].y * sc);
          afrag[2] = (__bf16)(aA[m][s].z * sc); afrag[3] = (__bf16)(aA[m][s].w * sc);
          afrag[4] = (__bf16)(aB[m][s].x * sc); afrag[5] = (__bf16)(aB[m][s].y * sc);
          afrag[6] = (__bf16)(aB[m][s].z * sc); afrag[7] = (__bf16)(aB[m][s].w * sc);
          acc[m] = __builtin_amdgcn_mfma_f32_16x16x32_bf16(afrag, bfrag, acc[m], 0, 0, 0);
        }
      }
    }
}

#define T3_WAIT(N) do { asm volatile("s_waitcnt vmcnt(" #N ")" ::: "memory"); \
                        __builtin_amdgcn_sched_barrier(0); } while (0)

__global__ __launch_bounds__(128) void third_kernel(const float* __restrict__ fc,
        const float* __restrict__ w3, float* __restrict__ part) {
    __shared__ T3Shared sh;
    int t = threadIdx.x;
    int nblk   = blockIdx.x & (T3_NBLK - 1);
    int kslice = blockIdx.x >> 5;
    int i0     = kslice >> 1;                        // i is constant per kslice
    int jbase  = (kslice & 1) * 32;

    // stage fcJ (transposed, padded) and fcI
    for (int idx = t; idx < 32*64; idx += 128) {
      int b = idx >> 5, jl = idx & 31;               // contiguous 32-float reads
      sh.fcJ[jl][b] = fc[b*64 + jbase + jl];
    }
    if (t < 64) sh.fcI[t] = fc[t*64 + i0];
    __syncthreads();                                 // drains vmcnt too

    int wave = t >> 6;
    int lane = t & 63;
    int l15  = lane & 15;
    int l4   = lane >> 4;
    int ocolbase = nblk * 32;

    // Hoisted raw A fragments: fc[m*16+l15][(s*4+l4)*8 .. +8)
    float4 aA[4][2], aB[4][2];
    #pragma unroll
    for (int m = 0; m < 4; ++m)
      #pragma unroll
      for (int s = 0; s < 2; ++s) {
        const float* pa = fc + (m*16 + l15)*64 + (s*4 + l4)*8;
        aA[m][s] = *(const float4*)pa;
        aB[m][s] = *(const float4*)(pa + 4);
      }

    f32x4 acc[4];
    #pragma unroll
    for (int m = 0; m < 4; ++m) acc[m] = (f32x4){0.f, 0.f, 0.f, 0.f};

    const char* w3b = (const char*)w3;
    size_t kb0 = (size_t)kslice * 8192;              // byte offset within column
    #define KB(c) (kb0 + (size_t)(c) * (CHUNK_IJ*64*4))

    t3_issue(w3b, sh.stage[0], wave, ocolbase, KB(0), lane);
    #pragma unroll 1
    for (int c = 0; c < NCHUNK - 2; c += 2) {
      t3_issue(w3b, sh.stage[1], wave, ocolbase, KB(c+1), lane);
      T3_WAIT(8);
      t3_compute(sh.stage[0], sh.fcJ, sh.fcI, c, wave, lane, aA, aB, acc);
      t3_issue(w3b, sh.stage[0], wave, ocolbase, KB(c+2), lane);
      T3_WAIT(8);
      t3_compute(sh.stage[1], sh.fcJ, sh.fcI, c+1, wave, lane, aA, aB, acc);
    }
    t3_issue(w3b, sh.stage[1], wave, ocolbase, KB(NCHUNK-1), lane);
    T3_WAIT(8);
    t3_compute(sh.stage[0], sh.fcJ, sh.fcI, NCHUNK-2, wave, lane, aA, aB, acc);
    T3_WAIT(0);
    t3_compute(sh.stage[1], sh.fcJ, sh.fcI, NCHUNK-1, wave, lane, aA, aB, acc);

    // D layout (verified m89): col = lane&15, row = (lane>>4)*4 + reg
    float* pt = part + (size_t)kslice * 64 * OUTN;
    int ocol = ocolbase + wave*16 + l15;
    #pragma unroll
    for (int m = 0; m < 4; ++m)
      #pragma unroll
      for (int r = 0; r < 4; ++r) {
        int row = m*16 + l4*4 + r;                   // batch
        pt[row * OUTN + ocol] = acc[m][r];
      }
}

// -------- sum the 128 K-slice partials into d_out ------------------------------
__global__ __launch_bounds__(256) void reduce_kernel(const float* __restrict__ part,
        float* __restrict__ out) {
    int idx = blockIdx.x * 256 + threadIdx.x;        // 65536 = 64*1024
    float s = 0.f;
    #pragma unroll 8
    for (int ks = 0; ks < KSLICES; ++ks)
      s += part[(size_t)ks * (64 * OUTN) + idx];
    out[idx] += s;
}

extern "C" void kernel_launch(void* const* d_in, const int* in_sizes, int n_in,
                              void* d_out, int out_size, void* d_ws, size_t ws_size,
                              hipStream_t stream) {
    const float* x   = (const float*)d_in[0];
    const float* w1  = (const float*)d_in[1];
    const float* b1  = (const float*)d_in[2];
    const float* w2  = (const float*)d_in[3];
    const float* b2  = (const float*)d_in[4];
    const float* wm  = (const float*)d_in[5];
    const float* bm  = (const float*)d_in[6];
    const float* wc  = (const float*)d_in[7];
    const float* bcv = (const float*)d_in[8];
    const float* w3  = (const float*)d_in[9];
    const float* b3  = (const float*)d_in[10];
    float* out = (float*)d_out;

    // workspace layout (floats): h1 | h2 | feat | fc | part  (~188 MB)
    float* ws   = (float*)d_ws;
    float* h1   = ws;                                // 64*32*112*112 = 25690112
    float* h2   = ws + 25690112;                     // 64*64*56*56   = 12845056
    float* feat = ws + 38535168;                     // 4096
    float* fcv  = ws + 38539264;                     // 4096
    float* part = ws + 38543360;                     // 128*64*1024   = 8388608

    conv1_kernel <<<3136, 256, 0, stream>>>(x, w1, b1, h1);
    conv2_kernel <<<3136, 256, 0, stream>>>(h1, w2, b2, h2);
    pool_kernel  <<<4096, 256, 0, stream>>>(h2, feat);
    center_kernel<<<1, 64, 0, stream>>>(feat, fcv);
    meancov_kernel<<<256, 256, 0, stream>>>(feat, fcv, wm, bm, wc, bcv, b3, out);
    third_kernel <<<T3_GRID, 128, 0, stream>>>(fcv, w3, part);
    reduce_kernel<<<256, 256, 0, stream>>>(part, out);
}

// Round 7
// 416.645 us; speedup vs baseline: 11.5087x; 1.3911x over previous
//
#include <hip/hip_runtime.h>
#include <hip/hip_bf16.h>

// Problem constants
#define BB   64
#define CIN  3
#define HH   224
#define WW   224
#define C1   32
#define H1   112
#define W1   112
#define C2   64
#define H2   56
#define W2   56
#define FEATN 64
#define OUTN 1024
#define K3TOT (FEATN*FEATN*FEATN)   // 262144

typedef __bf16 bf16x8 __attribute__((ext_vector_type(8)));
typedef float  f32x4  __attribute__((ext_vector_type(4)));
typedef unsigned int u32;

__device__ __forceinline__ void gload_lds16(const void* g, void* l) {
  __builtin_amdgcn_global_load_lds((const __attribute__((address_space(1))) u32*)g,
                                   (__attribute__((address_space(3))) u32*)l, 16, 0, 0);
}

// ---- halo: zero the 1-px border ring of h1T (64 x 114 x 114 x 32 bf16) ------
__global__ __launch_bounds__(256) void halo_kernel(__bf16* __restrict__ h1T) {
    int t = blockIdx.x * 256 + threadIdx.x;          // 64*452 = 28928
    if (t >= 64 * 452) return;
    int b = t / 452, s = t - b * 452;
    int row, col;
    if      (s < 114) { row = 0;        col = s; }
    else if (s < 228) { row = 113;      col = s - 114; }
    else if (s < 340) { row = s - 227;  col = 0; }     // rows 1..112
    else              { row = s - 339;  col = 113; }   // rows 1..112
    __bf16* p = h1T + (((size_t)b * 114 + row) * 114 + col) * 32;
    bf16x8 z = {};
    #pragma unroll
    for (int k = 0; k < 4; ++k) *(bf16x8*)(p + k * 8) = z;
}

// ---- w2frag: B-fragment-ready bf16 layout [j][q][lane][8] --------------------
// w2frag[((j*9+q)*64+lane)*8+e] = w2[oc=j*16+(lane&15)][c=(lane>>4)*8+e][q]
__global__ __launch_bounds__(256) void w2frag_kernel(const float* __restrict__ w2,
        __bf16* __restrict__ wf) {
    int t = blockIdx.x * 256 + threadIdx.x;          // 18432
    if (t >= 4 * 9 * 64 * 8) return;
    int e    = t & 7;
    int lane = (t >> 3) & 63;
    int q    = (t >> 9) % 9;
    int j    = t / 4608;
    int oc = j * 16 + (lane & 15);
    int c  = (lane >> 4) * 8 + e;
    wf[t] = (__bf16)w2[(oc * C1 + c) * 9 + q];
}

// ---------------- conv1: (64,3,224,224) -> relu -> h1T channels-last bf16 -----
__global__ __launch_bounds__(256) void conv1_kernel(const float* __restrict__ x,
        const float* __restrict__ w1, const float* __restrict__ b1,
        __bf16* __restrict__ h1T) {
    int pos = blockIdx.x * 256 + threadIdx.x;        // 64*112*112 = 802816
    int b   = pos / (H1 * W1);
    int rem = pos - b * (H1 * W1);
    int oy  = rem / W1;
    int ox  = rem - oy * W1;
    int iy0 = oy * 2 - 1, ix0 = ox * 2 - 1;

    float win[27];
    #pragma unroll
    for (int c = 0; c < CIN; ++c)
      #pragma unroll
      for (int dy = 0; dy < 3; ++dy)
        #pragma unroll
        for (int dx = 0; dx < 3; ++dx) {
          int iy = iy0 + dy, ix = ix0 + dx;
          bool ok = (iy >= 0) & (iy < HH) & (ix >= 0) & (ix < WW);
          win[c*9 + dy*3 + dx] = ok ? x[((b*CIN + c)*HH + iy)*WW + ix] : 0.f;
        }

    float acc[32];
    #pragma unroll
    for (int oc = 0; oc < C1; ++oc) acc[oc] = b1[oc];
    #pragma unroll
    for (int q = 0; q < 27; ++q) {
      float wv = win[q];
      #pragma unroll
      for (int oc = 0; oc < C1; ++oc)
        acc[oc] = fmaf(w1[oc*27 + q], wv, acc[oc]);
    }

    bf16x8 outv[4];
    #pragma unroll
    for (int k = 0; k < 32; ++k)
      outv[k >> 3][k & 7] = (__bf16)fmaxf(acc[k], 0.f);
    __bf16* dst = h1T + (((size_t)b * 114 + oy + 1) * 114 + ox + 1) * 32;
    #pragma unroll
    for (int k = 0; k < 4; ++k) *(bf16x8*)(dst + k * 8) = outv[k];
}

// ---------------- conv2: implicit-GEMM MFMA, M=128/block, N=64, K=9x32 --------
// Block: 256 thr (4 waves), handles 1 image x 2 output rows x 64 x (8 pad) x 64 oc.
// LDS: 5 x 114 x 32 bf16 tile (rows 2y0..2y0+4 of h1T), quarter-rotated by col
// (pre-swizzled global_load_lds source, linear dest; read applies (l4+col)&3).
__global__ __launch_bounds__(256) void conv2_kernel(const __bf16* __restrict__ h1T,
        const __bf16* __restrict__ wf, const float* __restrict__ b2,
        float* __restrict__ h2) {
    __shared__ __align__(16) char tile[2304 * 16];   // 36864 B (2280 real + pad)
    int t = threadIdx.x;
    int bid = blockIdx.x;                            // 64*28 = 1792
    int b  = bid / 28;
    int yt = bid - b * 28;
    int y0 = yt * 2;
    int w = t >> 6, lane = t & 63, l15 = lane & 15, l4 = lane >> 4;

    // ---- stage 5x114 sites (64B each) via gload_lds, 9 issues/wave
    const char* src_base = (const char*)(h1T + ((size_t)b * 114 + 2 * y0) * 114 * 32);
    #pragma unroll
    for (int i = 0; i < 9; ++i) {
      int g = (w * 9 + i) * 64 + lane;
      int site = g >> 2; site = site < 569 ? site : 569;
      int qp = g & 3;
      int r5 = site / 114;
      int col = site - r5 * 114;
      int ql = (qp - col) & 3;
      gload_lds16(src_base + (size_t)site * 64 + ql * 16, tile + (size_t)g * 16);
    }
    __syncthreads();

    // per-wave output tiles: mt = 2w+p, p in {0,1}
    int sbase[2], urot[2];
    #pragma unroll
    for (int p = 0; p < 2; ++p) {
      int mt = 2 * w + p;
      int yl = mt >> 2;
      int xl = ((mt & 3) << 4) + l15;
      int xe = xl < 55 ? xl : 55;                    // clamp padding lanes
      sbase[p] = ((yl * 2) * 114 + 2 * xe) * 64;
      urot[p]  = (l4 + 2 * xe) & 3;
    }

    f32x4 acc[2][4];
    #pragma unroll
    for (int p = 0; p < 2; ++p)
      #pragma unroll
      for (int j = 0; j < 4; ++j) acc[p][j] = (f32x4){0.f, 0.f, 0.f, 0.f};

    #pragma unroll
    for (int q = 0; q < 9; ++q) {
      int dy = q / 3, dx = q % 3;
      bf16x8 bw[4];
      #pragma unroll
      for (int j = 0; j < 4; ++j)
        bw[j] = *(const bf16x8*)(wf + ((j * 9 + q) * 64 + lane) * 8);
      bf16x8 af[2];
      #pragma unroll
      for (int p = 0; p < 2; ++p) {
        int addr = sbase[p] + (dy * 114 + dx) * 64 + (((urot[p] + dx) & 3) << 4);
        af[p] = *(const bf16x8*)(tile + addr);
      }
      #pragma unroll
      for (int p = 0; p < 2; ++p)
        #pragma unroll
        for (int j = 0; j < 4; ++j)
          acc[p][j] = __builtin_amdgcn_mfma_f32_16x16x32_bf16(af[p], bw[j], acc[p][j], 0, 0, 0);
    }

    // ---- epilogue: bias+relu, float4 stores (D: col=l15, row=l4*4+r)
    float bias[4];
    #pragma unroll
    for (int j = 0; j < 4; ++j) bias[j] = b2[j * 16 + l15];
    #pragma unroll
    for (int p = 0; p < 2; ++p) {
      int mt = 2 * w + p;
      int yv = y0 + (mt >> 2);
      int xb = ((mt & 3) << 4) + l4 * 4;
      if (xb <= 52) {
        #pragma unroll
        for (int j = 0; j < 4; ++j) {
          int oc = j * 16 + l15;
          float4 v;
          v.x = fmaxf(acc[p][j][0] + bias[j], 0.f);
          v.y = fmaxf(acc[p][j][1] + bias[j], 0.f);
          v.z = fmaxf(acc[p][j][2] + bias[j], 0.f);
          v.w = fmaxf(acc[p][j][3] + bias[j], 0.f);
          *(float4*)&h2[(size_t)(b * C2 + oc) * (H2 * W2) + yv * W2 + xb] = v;
        }
      }
    }
}

// ---------------- global average pool: (64,64,56,56) -> feat (64,64) ----------
__global__ __launch_bounds__(256) void pool_kernel(const float* __restrict__ h2,
        float* __restrict__ feat) {
    int bc = blockIdx.x;                             // 0..4095 = b*64 + c
    const float* p = h2 + (size_t)bc * (H2 * W2);
    float s = 0.f;
    for (int i = threadIdx.x; i < H2 * W2; i += 256) s += p[i];
    #pragma unroll
    for (int off = 32; off; off >>= 1) s += __shfl_down(s, off);
    __shared__ float red[4];
    if ((threadIdx.x & 63) == 0) red[threadIdx.x >> 6] = s;
    __syncthreads();
    if (threadIdx.x == 0)
      feat[bc] = (red[0] + red[1] + red[2] + red[3]) * (1.f / (H2 * W2));
}

// ---------------- center: fc = feat - rowmean(feat) ---------------------------
__global__ __launch_bounds__(64) void center_kernel(const float* __restrict__ feat,
        float* __restrict__ fc) {
    __shared__ float fl[FEATN * FEATN];
    int t = threadIdx.x;                             // 64 threads; t = b
    for (int i = t; i < FEATN * FEATN; i += 64) fl[i] = feat[i];
    __syncthreads();
    float m = 0.f;
    for (int c = 0; c < FEATN; ++c) m += fl[t*FEATN + c];
    m *= (1.f / FEATN);
    for (int c = 0; c < FEATN; ++c) fc[t*FEATN + c] = fl[t*FEATN + c] - m;
}

// -------- mean_feat + cov_feat + all biases -> WRITES d_out -------------------
__global__ __launch_bounds__(256) void meancov_kernel(const float* __restrict__ feat,
        const float* __restrict__ fc,
        const float* __restrict__ wm, const float* __restrict__ bm,
        const float* __restrict__ wc, const float* __restrict__ bcv,
        const float* __restrict__ b3, float* __restrict__ out) {
    __shared__ float featT[FEATN * FEATN];           // [c][b]
    __shared__ float fcT[FEATN * FEATN];             // [c][b]
    int t = threadIdx.x;
    for (int i = t; i < FEATN * FEATN; i += 256) {
      int b = i >> 6, c = i & 63;
      featT[c*64 + b] = feat[i];
      fcT[c*64 + b]   = fc[i];
    }
    __syncthreads();

    int b = t & 63;
    int o = blockIdx.x * 4 + (t >> 6);               // 256 blocks * 4 = 1024

    float fr[64];                                    // fc[b][*] in registers
    #pragma unroll
    for (int c4 = 0; c4 < 16; ++c4) {
      float4 v = *(const float4*)(fc + b*64 + c4*4);
      fr[c4*4+0]=v.x; fr[c4*4+1]=v.y; fr[c4*4+2]=v.z; fr[c4*4+3]=v.w;
    }

    float acc = bm[o] + bcv[o] + b3[o];
    #pragma unroll 8
    for (int c = 0; c < FEATN; ++c)
      acc = fmaf(featT[c*64 + b], wm[o*FEATN + c], acc);

    const float* wcrow = wc + (size_t)o * (FEATN * FEATN);
    #pragma unroll 1
    for (int c1 = 0; c1 < 64; ++c1) {
      float a2 = 0.f;
      #pragma unroll
      for (int c2 = 0; c2 < 64; ++c2)                // fr[c2]: static index
        a2 = fmaf(fr[c2], wcrow[c1*64 + c2], a2);
      acc = fmaf(fcT[c1*64 + b], a2, acc);           // LDS: 64 reads total
    }
    out[b * OUTN + o] = acc;
}

// -------- third-order term (identical to round 3; known-good, ~259us) ---------
#define T3_NBLK 32
#define KSLICES 128
#define CHUNK_IJ 2
#define NCHUNK 16           // 32 ij-pairs / CHUNK_IJ
#define T3_GRID (T3_NBLK * KSLICES)

struct T3Shared {
    float stage[2][32][CHUNK_IJ*64];   // [buf][block-col][k]  (32 KB)
    float fcJ[32][65];                 // fc[b][jbase+jl] as [jl][b], padded
    float fcI[64];                     // fc[b][i0]
};

__device__ __forceinline__ void t3_issue(const char* w3b, float (*buf)[CHUNK_IJ*64],
        int wave, int ocolbase, size_t kb, int lane) {
    int hi = lane >> 5;                 // which of the 2 cols this lane feeds
    int lo = (lane & 31) * 16;          // byte within the column's 512-B span
    #pragma unroll
    for (int i = 0; i < 8; ++i) {
      int colb = wave*16 + 2*i;         // block-local col of this inst (even)
      int col  = colb + hi;
      // inverse-swizzle the SOURCE so a swizzled READ sees w3[col][kb+koff]
      int srcoff = lo ^ ((col & 7) << 4);
      const char* src = w3b + (((size_t)(ocolbase + col)) << 20) + kb + srcoff;
      gload_lds16(src, &buf[colb][0]);
    }
}

__device__ __forceinline__ void t3_compute(const float (*buf)[CHUNK_IJ*64],
        const float (*fcJ)[65], const float* fcI,
        int c, int wave, int lane, const float4 aA[4][2], const float4 aB[4][2],
        f32x4 acc[4]) {
    int l15 = lane & 15, l4 = lane >> 4;
    int col = wave*16 + l15;
    int swz = (col & 7) << 4;
    int x0 = (l4*32) ^ swz;
    int x1 = (l4*32 + 16) ^ swz;
    const char* p = (const char*)&buf[col][0];
    #pragma unroll
    for (int e = 0; e < CHUNK_IJ; ++e) {
      int jl = c*CHUNK_IJ + e;
      float smul[4];
      #pragma unroll
      for (int m = 0; m < 4; ++m) {
        int bb = m*16 + l15;
        smul[m] = fcI[bb] * fcJ[jl][bb];
      }
      #pragma unroll
      for (int s = 0; s < 2; ++s) {
        int K = e*256 + s*128;                       // static after unroll
        float4 b0 = *(const float4*)(p + K + x0);
        float4 b1 = *(const float4*)(p + K + x1);
        bf16x8 bfrag;
        bfrag[0] = (__bf16)b0.x; bfrag[1] = (__bf16)b0.y;
        bfrag[2] = (__bf16)b0.z; bfrag[3] = (__bf16)b0.w;
        bfrag[4] = (__bf16)b1.x; bfrag[5] = (__bf16)b1.y;
        bfrag[6] = (__bf16)b1.z; bfrag[7] = (__bf16)b1.w;
        #pragma unroll
        for (int m = 0; m < 4; ++m) {
          float sc = smul[m];
          bf16x8 afrag;
          afrag[0] = (__bf16)(aA[m][s].x * sc); afrag[1] = (__bf16)(aA[m][s].y * sc);
          afrag[2] = (__bf16)(aA[m][s].z * sc); afrag[3] = (__bf16)(aA[m][s].w * sc);
          afrag[4] = (__bf16)(aB[m][s].x * sc); afrag[5] = (__bf16)(aB[m][s].y * sc);
          afrag[6] = (__bf16)(aB[m][s].z * sc); afrag[7] = (__bf16)(aB[m][s].w * sc);
          acc[m] = __builtin_amdgcn_mfma_f32_16x16x32_bf16(afrag, bfrag, acc[m], 0, 0, 0);
        }
      }
    }
}

#define T3_WAIT(N) do { asm volatile("s_waitcnt vmcnt(" #N ")" ::: "memory"); \
                        __builtin_amdgcn_sched_barrier(0); } while (0)

__global__ __launch_bounds__(128) void third_kernel(const float* __restrict__ fc,
        const float* __restrict__ w3, float* __restrict__ part) {
    __shared__ T3Shared sh;
    int t = threadIdx.x;
    int nblk   = blockIdx.x & (T3_NBLK - 1);
    int kslice = blockIdx.x >> 5;
    int i0     = kslice >> 1;                        // i is constant per kslice
    int jbase  = (kslice & 1) * 32;

    // stage fcJ (transposed, padded) and fcI
    for (int idx = t; idx < 32*64; idx += 128) {
      int b = idx >> 5, jl = idx & 31;               // contiguous 32-float reads
      sh.fcJ[jl][b] = fc[b*64 + jbase + jl];
    }
    if (t < 64) sh.fcI[t] = fc[t*64 + i0];
    __syncthreads();                                 // drains vmcnt too

    int wave = t >> 6;
    int lane = t & 63;
    int l15  = lane & 15;
    int l4   = lane >> 4;
    int ocolbase = nblk * 32;

    // Hoisted raw A fragments: fc[m*16+l15][(s*4+l4)*8 .. +8)
    float4 aA[4][2], aB[4][2];
    #pragma unroll
    for (int m = 0; m < 4; ++m)
      #pragma unroll
      for (int s = 0; s < 2; ++s) {
        const float* pa = fc + (m*16 + l15)*64 + (s*4 + l4)*8;
        aA[m][s] = *(const float4*)pa;
        aB[m][s] = *(const float4*)(pa + 4);
      }

    f32x4 acc[4];
    #pragma unroll
    for (int m = 0; m < 4; ++m) acc[m] = (f32x4){0.f, 0.f, 0.f, 0.f};

    const char* w3b = (const char*)w3;
    size_t kb0 = (size_t)kslice * 8192;              // byte offset within column
    #define KB(c) (kb0 + (size_t)(c) * (CHUNK_IJ*64*4))

    t3_issue(w3b, sh.stage[0], wave, ocolbase, KB(0), lane);
    #pragma unroll 1
    for (int c = 0; c < NCHUNK - 2; c += 2) {
      t3_issue(w3b, sh.stage[1], wave, ocolbase, KB(c+1), lane);
      T3_WAIT(8);
      t3_compute(sh.stage[0], sh.fcJ, sh.fcI, c, wave, lane, aA, aB, acc);
      t3_issue(w3b, sh.stage[0], wave, ocolbase, KB(c+2), lane);
      T3_WAIT(8);
      t3_compute(sh.stage[1], sh.fcJ, sh.fcI, c+1, wave, lane, aA, aB, acc);
    }
    t3_issue(w3b, sh.stage[1], wave, ocolbase, KB(NCHUNK-1), lane);
    T3_WAIT(8);
    t3_compute(sh.stage[0], sh.fcJ, sh.fcI, NCHUNK-2, wave, lane, aA, aB, acc);
    T3_WAIT(0);
    t3_compute(sh.stage[1], sh.fcJ, sh.fcI, NCHUNK-1, wave, lane, aA, aB, acc);

    // D layout (verified m89): col = lane&15, row = (lane>>4)*4 + reg
    float* pt = part + (size_t)kslice * 64 * OUTN;
    int ocol = ocolbase + wave*16 + l15;
    #pragma unroll
    for (int m = 0; m < 4; ++m)
      #pragma unroll
      for (int r = 0; r < 4; ++r) {
        int row = m*16 + l4*4 + r;                   // batch
        pt[row * OUTN + ocol] = acc[m][r];
      }
}

// -------- sum the 128 K-slice partials into d_out ------------------------------
__global__ __launch_bounds__(256) void reduce_kernel(const float* __restrict__ part,
        float* __restrict__ out) {
    int idx = blockIdx.x * 256 + threadIdx.x;        // 65536 = 64*1024
    float s = 0.f;
    #pragma unroll 8
    for (int ks = 0; ks < KSLICES; ++ks)
      s += part[(size_t)ks * (64 * OUTN) + idx];
    out[idx] += s;
}

extern "C" void kernel_launch(void* const* d_in, const int* in_sizes, int n_in,
                              void* d_out, int out_size, void* d_ws, size_t ws_size,
                              hipStream_t stream) {
    const float* x   = (const float*)d_in[0];
    const float* w1  = (const float*)d_in[1];
    const float* b1  = (const float*)d_in[2];
    const float* w2  = (const float*)d_in[3];
    const float* b2  = (const float*)d_in[4];
    const float* wm  = (const float*)d_in[5];
    const float* bm  = (const float*)d_in[6];
    const float* wc  = (const float*)d_in[7];
    const float* bcv = (const float*)d_in[8];
    const float* w3  = (const float*)d_in[9];
    const float* b3  = (const float*)d_in[10];
    float* out = (float*)d_out;

    // workspace layout (float offsets):
    //   h1T (bf16, 26,615,808 elems = 13,307,904 f) | h2 | feat | fc | part | w2frag
    float* ws    = (float*)d_ws;
    __bf16* h1T  = (__bf16*)ws;                      // 53.2 MB
    float* h2    = ws + 13307904;                    // 12,845,056 floats
    float* feat  = ws + 26152960;                    // 4096
    float* fcv   = ws + 26157056;                    // 4096
    float* part  = ws + 26161152;                    // 8,388,608
    __bf16* wfrg = (__bf16*)(ws + 34549760);         // 18,432 bf16

    halo_kernel  <<<113,  256, 0, stream>>>(h1T);
    w2frag_kernel<<<72,   256, 0, stream>>>(w2, wfrg);
    conv1_kernel <<<3136, 256, 0, stream>>>(x, w1, b1, h1T);
    conv2_kernel <<<1792, 256, 0, stream>>>(h1T, wfrg, b2, h2);
    pool_kernel  <<<4096, 256, 0, stream>>>(h2, feat);
    center_kernel<<<1,    64,  0, stream>>>(feat, fcv);
    meancov_kernel<<<256, 256, 0, stream>>>(feat, fcv, wm, bm, wc, bcv, b3, out);
    third_kernel <<<T3_GRID, 128, 0, stream>>>(fcv, w3, part);
    reduce_kernel<<<256,  256, 0, stream>>>(part, out);
}